// Round 1
// baseline (15234.686 us; speedup 1.0000x reference)
//
#include <hip/hip_runtime.h>
#include <math.h>

// Problem constants
#define NB   32      // batch
#define NT   300     // encoder frames
#define NE   1024    // encoder dim
#define NH   512     // hidden
#define NA   256     // attention dim
#define NC   10      // conv channels
#define NKW  201     // conv kernel width (2K+1), K=100
#define NV   10000   // vocab
#define NEMB 512     // embedding dim
#define NAO  512     // attention output dim
#define NTD  80      // decode steps
#define SCL  2.0f

__device__ __forceinline__ float sigf(float x){ return 1.f/(1.f+expf(-x)); }

// ---------------------------------------------------------------------------
// init: zbuf(dec_z)=0, dec_c=0, cvec_parts=0, prev=BOS, wbuf=w0(mask/len)
// ---------------------------------------------------------------------------
__global__ __launch_bounds__(256) void k_init(const int* __restrict__ enc_len,
    float* __restrict__ zbuf, float* __restrict__ dec_c, float* __restrict__ cp,
    float* __restrict__ wbuf, int* __restrict__ prev)
{
    int i = blockIdx.x*256 + threadIdx.x;           // 32768 threads
    if (i < NB*NH)   { zbuf[i]=0.f; dec_c[i]=0.f; }
    if (i < 2*NB*NAO)  cp[i]=0.f;
    if (i < NB*NT)   { int b=i/NT, t=i%NT; int len=enc_len[b];
                       wbuf[i] = (t<len)? 1.f/(float)len : 0.f; }
    if (i < NB)        prev[i]=1;                   // BOS
}

// ---------------------------------------------------------------------------
// Precompute pre_enc = enc_pad @ W_enc^T + b_enc.  M=9600,K=1024 exact tiles.
// 64x64 tile, KT=32, transposed LDS tiles for b128 fragment reads.
// ---------------------------------------------------------------------------
__global__ __launch_bounds__(256) void k_gemm_pre(const float* __restrict__ Ag,
    const float* __restrict__ Wg, const float* __restrict__ bias,
    float* __restrict__ Cg, int N)
{
    __shared__ float As[32][68];   // [kk][m]
    __shared__ float Bs[32][68];   // [kk][n]
    const int tid = threadIdx.x;
    const int m0 = blockIdx.y*64, n0 = blockIdx.x*64;
    const int r  = tid>>2, kg = (tid&3)*8;
    const int ty = tid>>4, tx = tid&15;
    float acc[4][4] = {};
    for (int k0 = 0; k0 < 1024; k0 += 32) {
        const float4 a0 = *(const float4*)(Ag + (size_t)(m0+r)*1024 + k0+kg);
        const float4 a1 = *(const float4*)(Ag + (size_t)(m0+r)*1024 + k0+kg+4);
        const float4 b0 = *(const float4*)(Wg + (size_t)(n0+r)*1024 + k0+kg);
        const float4 b1 = *(const float4*)(Wg + (size_t)(n0+r)*1024 + k0+kg+4);
        __syncthreads();
        As[kg+0][r]=a0.x; As[kg+1][r]=a0.y; As[kg+2][r]=a0.z; As[kg+3][r]=a0.w;
        As[kg+4][r]=a1.x; As[kg+5][r]=a1.y; As[kg+6][r]=a1.z; As[kg+7][r]=a1.w;
        Bs[kg+0][r]=b0.x; Bs[kg+1][r]=b0.y; Bs[kg+2][r]=b0.z; Bs[kg+3][r]=b0.w;
        Bs[kg+4][r]=b1.x; Bs[kg+5][r]=b1.y; Bs[kg+6][r]=b1.z; Bs[kg+7][r]=b1.w;
        __syncthreads();
        #pragma unroll
        for (int kk=0; kk<32; ++kk) {
            const float4 av = *(const float4*)&As[kk][ty*4];
            const float4 bv = *(const float4*)&Bs[kk][tx*4];
            const float a[4]={av.x,av.y,av.z,av.w};
            const float bb[4]={bv.x,bv.y,bv.z,bv.w};
            #pragma unroll
            for (int i=0;i<4;++i)
                #pragma unroll
                for (int j=0;j<4;++j) acc[i][j] += a[i]*bb[j];
        }
    }
    #pragma unroll
    for (int i=0;i<4;++i){
        const int m = m0 + ty*4 + i;
        #pragma unroll
        for (int j=0;j<4;++j)
            Cg[(size_t)m*N + n0 + tx*4 + j] = acc[i][j] + bias[n0+tx*4+j];
    }
}

// ---------------------------------------------------------------------------
// gates partials: gp[kp][b][n] = sum_{k in chunk} x[b][k]*Wcat[n][k]
// x = [emb[prev] (512) | cvec=cp0+cp1 (512) | dec_z (512)], Wcat = [W_ih|W_hh]
// grid (64, 4), 256 thr. Block: 32 n, all 32 b. Thread: 2b x 2n.
// ---------------------------------------------------------------------------
__global__ __launch_bounds__(256) void k_gates(const float* __restrict__ emb,
    const int* __restrict__ prev, const float* __restrict__ cp,
    const float* __restrict__ zbuf, const float* __restrict__ W_ih,
    const float* __restrict__ W_hh, float* __restrict__ gp)
{
    __shared__ float xt[32][68];
    const int tid = threadIdx.x;
    const int kp  = blockIdx.y;                    // 0..3, chunks of 384
    const int lane = tid&63, wv = tid>>6;
    const int bs = lane&15, nsl = lane>>4;
    const int n0 = blockIdx.x*32 + wv*8 + nsl*2;
    const int sb = tid>>3, sk = (tid&7)*8;
    const int pvs = prev[sb];
    const float* wih0 = W_ih + (size_t)n0*1024;
    const float* whh0 = W_hh + (size_t)n0*512;
    float a00=0.f,a01=0.f,a10=0.f,a11=0.f;
    for (int tile=0; tile<6; ++tile) {
        const int k0 = kp*384 + tile*64;
        const int gk = k0 + sk;
        float4 v0, v1;
        if (gk < 512) {
            const float4* p = (const float4*)(emb + (size_t)pvs*NEMB + gk);
            v0 = p[0]; v1 = p[1];
        } else if (gk < 1024) {
            const float4* p0 = (const float4*)(cp + sb*NAO + (gk-512));
            const float4* p1 = (const float4*)(cp + NB*NAO + sb*NAO + (gk-512));
            const float4 x0=p0[0], x1=p1[0], y0=p0[1], y1=p1[1];
            v0 = make_float4(x0.x+x1.x, x0.y+x1.y, x0.z+x1.z, x0.w+x1.w);
            v1 = make_float4(y0.x+y1.x, y0.y+y1.y, y0.z+y1.z, y0.w+y1.w);
        } else {
            const float4* p = (const float4*)(zbuf + sb*NH + (gk-1024));
            v0 = p[0]; v1 = p[1];
        }
        __syncthreads();
        *(float4*)&xt[sb][sk]   = v0;
        *(float4*)&xt[sb][sk+4] = v1;
        __syncthreads();
        const float* w0 = (k0 < 1024) ? wih0 + k0        : whh0 + (k0-1024);
        const float* w1 = (k0 < 1024) ? wih0 + 1024 + k0 : whh0 + 512 + (k0-1024);
        #pragma unroll
        for (int c=0;c<16;++c){
            const float4 xa = *(const float4*)&xt[bs][c*4];
            const float4 xb = *(const float4*)&xt[bs+16][c*4];
            const float4 wa = *(const float4*)(w0 + c*4);
            const float4 wb = *(const float4*)(w1 + c*4);
            a00 += xa.x*wa.x+xa.y*wa.y+xa.z*wa.z+xa.w*wa.w;
            a01 += xa.x*wb.x+xa.y*wb.y+xa.z*wb.z+xa.w*wb.w;
            a10 += xb.x*wa.x+xb.y*wa.y+xb.z*wa.z+xb.w*wa.w;
            a11 += xb.x*wb.x+xb.y*wb.y+xb.z*wb.z+xb.w*wb.w;
        }
    }
    float* g = gp + (size_t)(kp*NB)*2048;
    g[(size_t)bs*2048 + n0]        = a00;
    g[(size_t)bs*2048 + n0+1]      = a01;
    g[(size_t)(bs+16)*2048 + n0]   = a10;
    g[(size_t)(bs+16)*2048 + n0+1] = a11;
}

// ---------------------------------------------------------------------------
// FUSED LSTM + dec_t: one block per batch element, 512 threads.
// Phase 1: sum 4 gate partials + biases, update dec_c, write dec_z (global+LDS)
// Phase 2: dp[b][a] = sum_k dec_z[b][k]*W_dec[a][k]  (full, no partials)
//   layout: 32 groups of 16 lanes; group g handles a = g*8..g*8+7.
//   16 lanes of a group read the same W_dec row at k = l*4 + 64*i (coalesced
//   256B segments); dec_z held in registers; shfl-reduce over the 16 lanes.
// ---------------------------------------------------------------------------
__global__ __launch_bounds__(512) void k_lstm_dect(const float* __restrict__ gp,
    const float* __restrict__ b_ih, const float* __restrict__ b_hh,
    float* __restrict__ dec_c, float* __restrict__ zbuf,
    const float* __restrict__ W_dec, float* __restrict__ dp)
{
    __shared__ float zs[NH];
    const int b = blockIdx.x, tid = threadIdx.x;   // 512 threads, h = tid
    const int h = tid;
    float g[4];
    #pragma unroll
    for (int r=0;r<4;++r){
        float s = b_ih[r*512+h] + b_hh[r*512+h];
        #pragma unroll
        for (int kp=0;kp<4;++kp) s += gp[(size_t)(kp*NB+b)*2048 + r*512 + h];
        g[r]=s;
    }
    const int i = b*NH + h;
    const float c = sigf(g[1])*dec_c[i] + sigf(g[0])*tanhf(g[2]);
    dec_c[i] = c;
    const float z = sigf(g[3])*tanhf(c);
    zbuf[i] = z;
    zs[h]   = z;
    __syncthreads();

    const int grp = tid>>4, l = tid&15;
    float4 zr[8];
    #pragma unroll
    for (int q=0;q<8;++q) zr[q] = *(const float4*)&zs[l*4 + q*64];
    #pragma unroll
    for (int j=0;j<8;++j){
        const int a = grp*8 + j;
        const float* w = W_dec + (size_t)a*NH;
        float s = 0.f;
        #pragma unroll
        for (int q=0;q<8;++q){
            const float4 wv = *(const float4*)(w + l*4 + q*64);
            s += zr[q].x*wv.x + zr[q].y*wv.y + zr[q].z*wv.z + zr[q].w*wv.w;
        }
        s += __shfl_down(s, 8, 16);
        s += __shfl_down(s, 4, 16);
        s += __shfl_down(s, 2, 16);
        s += __shfl_down(s, 1, 16);
        if (l==0) dp[b*NA + a] = s;
    }
}

// ---------------------------------------------------------------------------
// attention scores e[b][t]: conv(w_prev) -> tanh(pre_enc+dec_t+att_conv).W_g
// grid (5 t-chunks of 60, 32 b), 256 thr.  dp is now a full (non-partial) buf.
// ---------------------------------------------------------------------------
__global__ __launch_bounds__(256) void k_escore(const float* __restrict__ pre_enc,
    const float* __restrict__ wprev, const float* __restrict__ ck,
    const float* __restrict__ W_att, const float* __restrict__ dp,
    const float* __restrict__ W_g, float* __restrict__ ebuf)
{
    __shared__ float w_h[260];
    __shared__ float ck_s[NC*NKW];     // 2010
    __shared__ float wt_s[NA*NC];      // 2560
    __shared__ float dt_s[NA];
    __shared__ float wg_s[NA];
    __shared__ float cv_s[60*NC];      // 600
    __shared__ float ep_s[60][4];
    const int tid = threadIdx.x;
    const int b = blockIdx.y, t0 = blockIdx.x*60;
    for (int i=tid;i<260;i+=256){ const int gt=t0-100+i;
        w_h[i] = (gt>=0 && gt<NT)? wprev[b*NT+gt] : 0.f; }
    for (int i=tid;i<NC*NKW;i+=256) ck_s[i]=ck[i];
    for (int i=tid;i<NA*NC;i+=256)  wt_s[i]=W_att[i];
    dt_s[tid&255] = dp[b*NA+(tid&255)];
    wg_s[tid&255] = W_g[tid&255];
    __syncthreads();
    for (int i=tid;i<60*NC;i+=256){
        const int tl=i/NC, ch=i%NC;
        float s=0.f;
        const float* wp  = &w_h[tl];
        const float* ckp = &ck_s[ch*NKW];
        for (int k=0;k<NKW;++k) s += wp[k]*ckp[k];
        cv_s[i]=s;
    }
    __syncthreads();
    const int tq = tid&3, tl = tid>>2;
    if (tl < 60) {
        float cv[NC];
        #pragma unroll
        for (int ch=0;ch<NC;++ch) cv[ch]=cv_s[tl*NC+ch];
        const float* pe = pre_enc + (size_t)(b*NT + t0 + tl)*NA;
        float part=0.f;
        for (int i=0;i<64;++i){
            const int aa = tq + 4*i;               // interleaved: bank-spread
            float attc = 0.f;
            #pragma unroll
            for (int ch=0;ch<NC;++ch) attc += cv[ch]*wt_s[aa*NC+ch];
            part += tanhf(pe[aa] + dt_s[aa] + attc) * wg_s[aa];
        }
        ep_s[tl][tq] = part;
    }
    __syncthreads();
    if (tid < 60)
        ebuf[b*NT + t0 + tid] = ep_s[tid][0]+ep_s[tid][1]+ep_s[tid][2]+ep_s[tid][3];
}

// ---------------------------------------------------------------------------
// softmax (recomputed per block) + ctx[b][d] = sum_t w[b,t]*enc_pad[b,t,d]
// grid (4 d-chunks of 256, 32 b); block x==0 also writes wbuf + out_ws
// ---------------------------------------------------------------------------
__global__ __launch_bounds__(256) void k_ctx(const float* __restrict__ ebuf,
    const float* __restrict__ enc_pad, float* __restrict__ ctx,
    float* __restrict__ wbuf, float* __restrict__ out_ws, int step)
{
    __shared__ float es[NT], wsm[NT], red[256];
    const int tid=threadIdx.x, b=blockIdx.y, d0=blockIdx.x*256;
    for (int t=tid;t<NT;t+=256) es[t]=ebuf[b*NT+t];
    __syncthreads();
    float m=-3.4e38f;
    for (int t=tid;t<NT;t+=256) m=fmaxf(m,es[t]);
    red[tid]=m; __syncthreads();
    for (int s=128;s>0;s>>=1){ if(tid<s) red[tid]=fmaxf(red[tid],red[tid+s]); __syncthreads(); }
    m=red[0]; __syncthreads();
    float ss=0.f;
    for (int t=tid;t<NT;t+=256) ss+=expf(SCL*(es[t]-m));
    red[tid]=ss; __syncthreads();
    for (int s=128;s>0;s>>=1){ if(tid<s) red[tid]+=red[tid+s]; __syncthreads(); }
    const float inv = 1.f/red[0];
    for (int t=tid;t<NT;t+=256){
        const float w = expf(SCL*(es[t]-m))*inv;
        wsm[t]=w;
        if (blockIdx.x==0){ wbuf[b*NT+t]=w; out_ws[((size_t)b*NTD+step)*NT+t]=w; }
    }
    __syncthreads();
    const float* ep = enc_pad + (size_t)b*NT*NE + d0 + tid;
    float acc=0.f;
    #pragma unroll 4
    for (int t=0;t<NT;++t) acc += wsm[t]*ep[(size_t)t*NE];
    ctx[b*NE + d0 + tid] = acc;
}

// ---------------------------------------------------------------------------
// cvec partials: cp[kp][b][o] = sum_{k chunk} ctx[b][k]*W_o[o][k] (+b_o in kp0)
// grid (16, 2), 256 thr, thread 2b x 2n, global-direct.
// ---------------------------------------------------------------------------
__global__ __launch_bounds__(256) void k_cvec(const float* __restrict__ ctx,
    const float* __restrict__ W_o, const float* __restrict__ b_o,
    float* __restrict__ cp)
{
    const int tid=threadIdx.x, kp=blockIdx.y;
    const int lane=tid&63, wv=tid>>6, bs=lane&15, nsl=lane>>4;
    const int n0 = blockIdx.x*32 + wv*8 + nsl*2;
    const float* x0 = ctx + bs*NE;
    const float* x1 = ctx + (bs+16)*NE;
    const float* w0 = W_o + (size_t)n0*NE;
    const float* w1 = w0 + NE;
    float a00=0.f,a01=0.f,a10=0.f,a11=0.f;
    const int kb = kp*512;
    #pragma unroll 8
    for (int c=0;c<128;++c){
        const int k = kb + c*4;
        const float4 xa = *(const float4*)(x0+k);
        const float4 xb = *(const float4*)(x1+k);
        const float4 wa = *(const float4*)(w0+k);
        const float4 wb = *(const float4*)(w1+k);
        a00 += xa.x*wa.x+xa.y*wa.y+xa.z*wa.z+xa.w*wa.w;
        a01 += xa.x*wb.x+xa.y*wb.y+xa.z*wb.z+xa.w*wb.w;
        a10 += xb.x*wa.x+xb.y*wa.y+xb.z*wa.z+xb.w*wa.w;
        a11 += xb.x*wb.x+xb.y*wb.y+xb.z*wb.z+xb.w*wb.w;
    }
    const float bo0 = (kp==0)? b_o[n0]   : 0.f;
    const float bo1 = (kp==0)? b_o[n0+1] : 0.f;
    cp[(size_t)(kp*NB+bs)*NAO + n0]        = a00 + bo0;
    cp[(size_t)(kp*NB+bs)*NAO + n0+1]      = a01 + bo1;
    cp[(size_t)(kp*NB+bs+16)*NAO + n0]     = a10 + bo0;
    cp[(size_t)(kp*NB+bs+16)*NAO + n0+1]   = a11 + bo1;
}

// ---------------------------------------------------------------------------
// logits partials: lp[kp][b][v] = sum_{k chunk} y[b][k]*W_out[v][k]
// y = [dec_z (512) | cvec = cp0+cp1 (512)].  grid (313, 2), 256 thr.
// ---------------------------------------------------------------------------
__global__ __launch_bounds__(256) void k_logits(const float* __restrict__ zbuf,
    const float* __restrict__ cp, const float* __restrict__ W_out,
    float* __restrict__ lp)
{
    __shared__ float xt[32][68];
    const int tid=threadIdx.x, kp=blockIdx.y;
    const int lane=tid&63, wv=tid>>6, bs=lane&15, nsl=lane>>4;
    const int n0 = blockIdx.x*32 + wv*8 + nsl*2;
    const int rn0 = (n0   < NV)? n0   : NV-1;
    const int rn1 = (n0+1 < NV)? n0+1 : NV-1;
    const float* w0 = W_out + (size_t)rn0*1024;
    const float* w1 = W_out + (size_t)rn1*1024;
    const int sb = tid>>3, sk = (tid&7)*8;
    float a00=0.f,a01=0.f,a10=0.f,a11=0.f;
    for (int tile=0; tile<8; ++tile) {
        const int k0 = kp*512 + tile*64;
        const int gk = k0 + sk;
        float4 v0, v1;
        if (gk < 512) {
            const float4* p = (const float4*)(zbuf + sb*NH + gk);
            v0 = p[0]; v1 = p[1];
        } else {
            const float4* p0 = (const float4*)(cp + sb*NAO + (gk-512));
            const float4* p1 = (const float4*)(cp + NB*NAO + sb*NAO + (gk-512));
            const float4 x0=p0[0], x1=p1[0], y0=p0[1], y1=p1[1];
            v0 = make_float4(x0.x+x1.x, x0.y+x1.y, x0.z+x1.z, x0.w+x1.w);
            v1 = make_float4(y0.x+y1.x, y0.y+y1.y, y0.z+y1.z, y0.w+y1.w);
        }
        __syncthreads();
        *(float4*)&xt[sb][sk]   = v0;
        *(float4*)&xt[sb][sk+4] = v1;
        __syncthreads();
        #pragma unroll
        for (int c=0;c<16;++c){
            const float4 xa = *(const float4*)&xt[bs][c*4];
            const float4 xb = *(const float4*)&xt[bs+16][c*4];
            const float4 wa = *(const float4*)(w0 + k0 + c*4);
            const float4 wb = *(const float4*)(w1 + k0 + c*4);
            a00 += xa.x*wa.x+xa.y*wa.y+xa.z*wa.z+xa.w*wa.w;
            a01 += xa.x*wb.x+xa.y*wb.y+xa.z*wb.z+xa.w*wb.w;
            a10 += xb.x*wa.x+xb.y*wa.y+xb.z*wa.z+xb.w*wa.w;
            a11 += xb.x*wb.x+xb.y*wb.y+xb.z*wb.z+xb.w*wb.w;
        }
    }
    if (n0 < NV){
        lp[(size_t)(kp*NB+bs)*NV + n0]    = a00;
        lp[(size_t)(kp*NB+bs+16)*NV + n0] = a10;
    }
    if (n0+1 < NV){
        lp[(size_t)(kp*NB+bs)*NV + n0+1]    = a01;
        lp[(size_t)(kp*NB+bs+16)*NV + n0+1] = a11;
    }
}

// ---------------------------------------------------------------------------
// finalize: logits = lp0+lp1+b_out -> d_out; argmax (first-idx) + logsumexp
// ---------------------------------------------------------------------------
__global__ __launch_bounds__(256) void k_fin(const float* __restrict__ lp,
    const float* __restrict__ b_out, int step, float* __restrict__ out_logits,
    int* __restrict__ prev, float* __restrict__ out_preds, float* __restrict__ out_ylp)
{
    __shared__ float rv[256];
    __shared__ int   ri[256];
    const int b=blockIdx.x, tid=threadIdx.x;
    const float* p0 = lp + (size_t)b*NV;
    const float* p1 = lp + (size_t)(NB+b)*NV;
    float* dst = out_logits + ((size_t)b*NTD + step)*NV;
    float m=-3.4e38f; int mi=NV;
    for (int v=tid; v<NV; v+=256){
        const float l = p0[v]+p1[v]+b_out[v];
        dst[v]=l;
        if (l>m){ m=l; mi=v; }
    }
    rv[tid]=m; ri[tid]=mi; __syncthreads();
    for (int s=128;s>0;s>>=1){
        if (tid<s){
            if (rv[tid+s]>rv[tid] || (rv[tid+s]==rv[tid] && ri[tid+s]<ri[tid])){
                rv[tid]=rv[tid+s]; ri[tid]=ri[tid+s];
            }
        }
        __syncthreads();
    }
    m=rv[0]; mi=ri[0]; __syncthreads();
    float ss=0.f;
    for (int v=tid; v<NV; v+=256) ss += expf(dst[v]-m);
    rv[tid]=ss; __syncthreads();
    for (int s=128;s>0;s>>=1){ if(tid<s) rv[tid]+=rv[tid+s]; __syncthreads(); }
    if (tid==0){
        prev[b]=mi;
        out_preds[b*NTD+step]=(float)mi;
        out_ylp[b*NTD+step]=-logf(rv[0]);
    }
}

// ---------------------------------------------------------------------------
extern "C" void kernel_launch(void* const* d_in, const int* in_sizes, int n_in,
                              void* d_out, int out_size, void* d_ws, size_t ws_size,
                              hipStream_t stream)
{
    const float* enc_pad   = (const float*)d_in[0];
    const int*   enc_len   = (const int*)d_in[1];
    const float* embedding = (const float*)d_in[2];
    const float* W_ih      = (const float*)d_in[3];
    const float* b_ih      = (const float*)d_in[4];
    const float* W_hh      = (const float*)d_in[5];
    const float* b_hh      = (const float*)d_in[6];
    const float* W_enc     = (const float*)d_in[7];
    const float* b_enc     = (const float*)d_in[8];
    const float* W_dec     = (const float*)d_in[9];
    const float* W_att     = (const float*)d_in[10];
    const float* conv_k    = (const float*)d_in[11];
    const float* W_g       = (const float*)d_in[12];
    const float* W_o       = (const float*)d_in[13];
    const float* b_o       = (const float*)d_in[14];
    const float* W_out     = (const float*)d_in[15];
    const float* b_out     = (const float*)d_in[16];

    float* out_logits = (float*)d_out;                        // [B,TD,V]
    float* out_ylp    = out_logits + (size_t)NB*NTD*NV;       // [B,TD]
    float* out_preds  = out_ylp + NB*NTD;                     // [B,TD]
    float* out_ws     = out_preds + NB*NTD;                   // [B,TD,T]

    float* f = (float*)d_ws;
    float* pre_enc = f;                                   // 9600*256
    float* zbuf    = pre_enc + (size_t)NB*NT*NA;          // 32*512  (dec_z)
    float* dec_c   = zbuf + NB*NH;                        // 32*512
    float* gp      = dec_c + NB*NH;                       // 4*32*2048
    float* dp      = gp + 4*NB*2048;                      // 32*256 (full dec_t; region sized 2x)
    float* cp      = dp + 2*NB*NA;                        // 2*32*512
    float* ebuf    = cp + 2*NB*NAO;                       // 32*300
    float* wbuf    = ebuf + NB*NT;                        // 32*300
    float* ctx     = wbuf + NB*NT;                        // 32*1024
    float* lp      = ctx + NB*NE;                         // 2*32*10000
    int*   prev    = (int*)(lp + (size_t)2*NB*NV);        // 32

    k_init<<<128, 256, 0, stream>>>(enc_len, zbuf, dec_c, cp, wbuf, prev);
    k_gemm_pre<<<dim3(NA/64, NB*NT/64), 256, 0, stream>>>(enc_pad, W_enc, b_enc, pre_enc, NA);

    for (int s = 0; s < NTD; ++s) {
        k_gates    <<<dim3(64,4),  256, 0, stream>>>(embedding, prev, cp, zbuf, W_ih, W_hh, gp);
        k_lstm_dect<<<NB,          512, 0, stream>>>(gp, b_ih, b_hh, dec_c, zbuf, W_dec, dp);
        k_escore   <<<dim3(5,32),  256, 0, stream>>>(pre_enc, wbuf, conv_k, W_att, dp, W_g, ebuf);
        k_ctx      <<<dim3(4,32),  256, 0, stream>>>(ebuf, enc_pad, ctx, wbuf, out_ws, s);
        k_cvec     <<<dim3(16,2),  256, 0, stream>>>(ctx, W_o, b_o, cp);
        k_logits   <<<dim3(313,2), 256, 0, stream>>>(zbuf, cp, W_out, lp);
        k_fin      <<<32,          256, 0, stream>>>(lp, b_out, s, out_logits, prev, out_preds, out_ylp);
    }
}